// Round 12
// baseline (119.955 us; speedup 1.0000x reference)
//
#include <hip/hip_runtime.h>
#include <math.h>

#define Bn 4
#define Tn 12
#define Nn 512
#define Dn 128
#define Ln 4
#define Hn 64

typedef __attribute__((ext_vector_type(8))) short short8;
typedef __attribute__((ext_vector_type(4))) float f32x4;
typedef _Float16 h2 __attribute__((ext_vector_type(2)));

__device__ __forceinline__ unsigned short f2bf(float f) {
    unsigned int u = __float_as_uint(f);
    unsigned int r = (u + 0x7FFF + ((u >> 16) & 1)) >> 16;   // RNE
    return (unsigned short)r;
}
__device__ __forceinline__ float bf2f(unsigned short s) {
    return __uint_as_float(((unsigned int)s) << 16);
}
__device__ __forceinline__ float fdot2(h2 a, h2 b, float c) {
#if defined(__has_builtin)
#if __has_builtin(__builtin_amdgcn_fdot2)
    return __builtin_amdgcn_fdot2(a, b, c, false);
#else
    return c + (float)a.x*(float)b.x + (float)a.y*(float)b.y;
#endif
#else
    return c + (float)a.x*(float)b.x + (float)a.y*(float)b.y;
#endif
}

// ============ K0: weight pre-pack (once): W1/W2/Ws1 -> bf16, MFMA-B layout ============
__global__ __launch_bounds__(256) void k_prep(
    const float* __restrict__ W1, const float* __restrict__ W2, const float* __restrict__ Ws1,
    unsigned short* __restrict__ w1p, unsigned short* __restrict__ w2p,
    unsigned short* __restrict__ wsp)
{
    int g = blockIdx.x*256 + threadIdx.x;
    unsigned short tmp[8];
    if (g < 4096) {                       // w1p
        int lag = g >> 10, r = g & 1023;
        int n = r >> 4, k8 = r & 15;
        #pragma unroll
        for (int j = 0; j < 8; ++j) tmp[j] = f2bf(W1[(size_t)(lag*128 + k8*8 + j)*64 + n]);
        *(short8*)(w1p + (size_t)lag*8192 + n*128 + k8*8) = *(const short8*)tmp;
    } else if (g < 8192) {                // w2p
        int r = g - 4096;
        int n = r >> 5, k8 = r & 31;
        #pragma unroll
        for (int j = 0; j < 8; ++j) tmp[j] = f2bf(W2[(size_t)(k8*8 + j)*128 + n]);
        *(short8*)(w2p + (size_t)n*256 + k8*8) = *(const short8*)tmp;
    } else {                              // wsp
        int r = g - 8192;
        int tgt = r >> 11, r2 = r & 2047;
        int n = r2 >> 4, k8 = r2 & 15;
        #pragma unroll
        for (int j = 0; j < 8; ++j) tmp[j] = f2bf(Ws1[(size_t)(tgt*128 + k8*8 + j)*128 + n]);
        *(short8*)(wsp + (size_t)tgt*16384 + n*128 + k8*8) = *(const short8*)tmp;
    }
}

// ============ K1: fused lag-encoder, 512 threads (R5, proven) ============
// Resets maxslot[0..3] AND done[0..3] (= slots[4..7]) for the spin-fused k_mm2.
__global__ __launch_bounds__(512) void k_enc(
    const float* __restrict__ x,  const float* __restrict__ b1,
    const float* __restrict__ b2, const float* __restrict__ bs1,
    const unsigned short* __restrict__ w1p, const unsigned short* __restrict__ w2p,
    const unsigned short* __restrict__ wsp,
    unsigned short* __restrict__ spb, unsigned short* __restrict__ tpb,
    unsigned int* __restrict__ slots)
{
    __shared__ __align__(16) unsigned short xAll[4][16*136];
    __shared__ __align__(16) unsigned short hA[16*264];
    __shared__ __align__(16) unsigned short aggA[16*136];
    int tid  = threadIdx.x;
    int bid  = blockIdx.x;
    int wv   = __builtin_amdgcn_readfirstlane(tid >> 6);
    int lane = tid & 63;
    if (bid == 0 && tid < 2*Bn) slots[tid] = 0u;   // maxslot[0..3] + done[0..3]

    int r0 = bid * 16;                      // never straddles a batch
    int bb = r0 >> 9, n0 = r0 & 511;
    int m = lane & 15, q = lane >> 4;
    int colL = lane & 15, rq = lane >> 4;

    // --- stage all 4 lag x-tiles ---
    for (int v = tid; v < 2048; v += 512) {
        int lag = v >> 9, r = v & 511;
        int row = r >> 5, c4 = r & 31;
        const float4* xs = (const float4*)(x + ((size_t)(bb*Tn + (Tn-1-lag))*Nn + n0)*Dn);
        float4 f = xs[row*32 + c4];
        ushort4 o = { f2bf(f.x), f2bf(f.y), f2bf(f.z), f2bf(f.w) };
        *(ushort4*)&xAll[lag][row*136 + c4*4] = o;
    }
    __syncthreads();

    // --- 1a: hA = relu(x_lag @ W1[lag] + b1[lag]); wave = (lag, 32-col half) ---
    {
        int lag = wv >> 1, hf = wv & 1;
        f32x4 acc[2] = {{0.f,0.f,0.f,0.f},{0.f,0.f,0.f,0.f}};
        #pragma unroll
        for (int ks = 0; ks < 4; ++ks) {
            short8 af = *(const short8*)&xAll[lag][m*136 + ks*32 + q*8];
            #pragma unroll
            for (int nt = 0; nt < 2; ++nt) {
                short8 bg = *(const short8*)(w1p + (size_t)lag*8192 + (hf*32 + nt*16 + m)*128 + ks*32 + q*8);
                acc[nt] = __builtin_amdgcn_mfma_f32_16x16x32_bf16(af, bg, acc[nt], 0, 0, 0);
            }
        }
        #pragma unroll
        for (int nt = 0; nt < 2; ++nt) {
            int ncol = hf*32 + nt*16 + colL;
            float bv = b1[lag*Hn + ncol];
            #pragma unroll
            for (int reg = 0; reg < 4; ++reg)
                hA[(rq*4+reg)*264 + lag*64 + ncol] = f2bf(fmaxf(acc[nt][reg] + bv, 0.f));
        }
    }
    __syncthreads();

    // --- 1b: aggA = 0.25*(hA @ W2stacked + sum_l b2[l]) ---
    {
        f32x4 acc = {0.f,0.f,0.f,0.f};
        #pragma unroll
        for (int ks = 0; ks < 8; ++ks) {
            short8 af = *(const short8*)&hA[m*264 + ks*32 + q*8];
            short8 bg = *(const short8*)(w2p + (size_t)(wv*16 + m)*256 + ks*32 + q*8);
            acc = __builtin_amdgcn_mfma_f32_16x16x32_bf16(af, bg, acc, 0, 0, 0);
        }
        int col = wv*16 + colL;
        float b2s = b2[col] + b2[Dn+col] + b2[2*Dn+col] + b2[3*Dn+col];
        #pragma unroll
        for (int reg = 0; reg < 4; ++reg)
            aggA[(rq*4+reg)*136 + col] = f2bf(0.25f*(acc[reg] + b2s));
    }
    __syncthreads();

    // --- 1c: sp/tp = aggA@Ws1; wave = (tgt, 32-col range) ---
    {
        int tgt = wv >> 2, wv4 = wv & 3;
        f32x4 acc[2] = {{0.f,0.f,0.f,0.f},{0.f,0.f,0.f,0.f}};
        #pragma unroll
        for (int ks = 0; ks < 4; ++ks) {
            short8 af = *(const short8*)&aggA[m*136 + ks*32 + q*8];
            #pragma unroll
            for (int nt = 0; nt < 2; ++nt) {
                short8 bg = *(const short8*)(wsp + (size_t)tgt*16384 + (wv4*32 + nt*16 + m)*128 + ks*32 + q*8);
                acc[nt] = __builtin_amdgcn_mfma_f32_16x16x32_bf16(af, bg, acc[nt], 0, 0, 0);
            }
        }
        unsigned short* dst = tgt ? tpb : spb;
        #pragma unroll
        for (int nt = 0; nt < 2; ++nt) {
            int n = wv4*32 + nt*16 + colL;
            float bv = tgt ? 0.f : bs1[n];
            #pragma unroll
            for (int reg = 0; reg < 4; ++reg) {
                _Float16 hv = (_Float16)(acc[nt][reg] + bv);
                dst[(size_t)(r0 + rq*4 + reg)*Dn + n] = __builtin_bit_cast(unsigned short, hv);
            }
        }
    }
}

// ============ K2: pairwise scorer, 512 threads (R11, proven) -> adj_b + adj_pk ============
__global__ __launch_bounds__(512) void k_score(
    const unsigned short* __restrict__ spb, const unsigned short* __restrict__ tpb,
    const float* __restrict__ Ws2, const float* __restrict__ bs2,
    unsigned short* __restrict__ adj_b, unsigned short* __restrict__ adj_pk)
{
    __shared__ unsigned int spl[64*65];     // f16 pairs, stride 65 uints (bank-safe)
    __shared__ unsigned int tpl[64*65];
    __shared__ unsigned int wl[64];
    int tid = threadIdx.x;
    int wv = __builtin_amdgcn_readfirstlane(tid >> 6);   // 0..7
    int lane = tid & 63;
    int bz = blockIdx.z;
    int i0b = blockIdx.y * 64, j0b = blockIdx.x * 64;
    const unsigned short* spr = spb + (size_t)bz*Nn*Dn;
    const unsigned short* tpr = tpb + (size_t)bz*Nn*Dn;

    for (int v = tid; v < 1024; v += 512) {           // both tiles, row-major f16 pairs
        int row = v >> 4, c = v & 15;
        uint4 gs = *(const uint4*)(spr + (size_t)(i0b+row)*Dn + c*8);
        uint4 gt = *(const uint4*)(tpr + (size_t)(j0b+row)*Dn + c*8);
        spl[row*65 + c*4 + 0] = gs.x; spl[row*65 + c*4 + 1] = gs.y;
        spl[row*65 + c*4 + 2] = gs.z; spl[row*65 + c*4 + 3] = gs.w;
        tpl[row*65 + c*4 + 0] = gt.x; tpl[row*65 + c*4 + 1] = gt.y;
        tpl[row*65 + c*4 + 2] = gt.z; tpl[row*65 + c*4 + 3] = gt.w;
    }
    if (tid < 64) {
        h2 hw = { (_Float16)Ws2[tid*2], (_Float16)Ws2[tid*2+1] };
        wl[tid] = __builtin_bit_cast(unsigned int, hw);
    }
    __syncthreads();

    int iq = lane >> 4, jq = lane & 15;
    int iw = wv*8 + iq*2;                             // 8 waves x 4 iq x 2 rows = 64 rows
    float acc[2][4] = {};
    #pragma unroll 4
    for (int c = 0; c < 64; ++c) {                    // one f16 d-pair per iter
        h2 wp = __builtin_bit_cast(h2, wl[c]);
        h2 sh[2], th[4];
        #pragma unroll
        for (int ii = 0; ii < 2; ++ii) sh[ii] = __builtin_bit_cast(h2, spl[(iw+ii)*65 + c]);
        #pragma unroll
        for (int jj = 0; jj < 4; ++jj) th[jj] = __builtin_bit_cast(h2, tpl[(jq*4+jj)*65 + c]);
        #pragma unroll
        for (int ii = 0; ii < 2; ++ii)
            #pragma unroll
            for (int jj = 0; jj < 4; ++jj) {
                h2 r = __builtin_elementwise_max(sh[ii] + th[jj], (h2){(_Float16)0.f,(_Float16)0.f});
                acc[ii][jj] = fdot2(r, wp, acc[ii][jj]);
            }
    }
    float bsv = bs2[0];
    int i0 = i0b + iw;
    int j0 = j0b + jq*4;
    float vals[2][4];
    #pragma unroll
    for (int ii = 0; ii < 2; ++ii) {
        int i = i0 + ii;
        #pragma unroll
        for (int jj = 0; jj < 4; ++jj) {
            float z = acc[ii][jj] + bsv;
            float sc = 1.f/(1.f + __expf(-z));
            int j = j0 + jj;
            vals[ii][jj] = (sc > 0.1f && i != j) ? sc : 0.f;
        }
    }
    size_t base = (size_t)bz << 18;
    #pragma unroll
    for (int ii = 0; ii < 2; ++ii) {
        ushort4 rv = make_ushort4(f2bf(vals[ii][0]), f2bf(vals[ii][1]),
                                  f2bf(vals[ii][2]), f2bf(vals[ii][3]));
        *(ushort4*)(adj_b + base + (size_t)(i0+ii)*Nn + j0) = rv;
    }
    // fragment-packed writes: per jj, the 2 ii values are t0..t0+1 of one octet (4B store)
    int kblk = i0 >> 5, qq = (i0 >> 3) & 3, t0 = i0 & 7;
    #pragma unroll
    for (int jj = 0; jj < 4; ++jj) {
        int j = j0 + jj;
        int jt = j >> 4, mm = j & 15;
        ushort2 cv = make_ushort2(f2bf(vals[0][jj]), f2bf(vals[1][jj]));
        *(ushort2*)(adj_pk + base + (size_t)(kblk*32 + jt)*512 + (qq*16 + mm)*8 + t0) = cv;
    }
}

// ============ K3: a2 = adj @ adj; A via LDS dbuf (1 barrier/kt), B direct from adj_pk ============
__global__ __launch_bounds__(256) void k_mm1(
    const unsigned short* __restrict__ adj_b, const unsigned short* __restrict__ adj_pk,
    unsigned short* __restrict__ a2b)
{
    __shared__ unsigned short Als[2][64*72];
    int tid = threadIdx.x;
    int wv = __builtin_amdgcn_readfirstlane(tid >> 6);
    int lane = tid & 63;
    int b = blockIdx.z, i0 = blockIdx.y*64, j0 = blockIdx.x*64;
    size_t base = (size_t)b << 18;
    const unsigned short* Ab = adj_b + base;
    const unsigned short* pkB = adj_pk + base + (size_t)lane*8;
    int wm = wv >> 1, wn = wv & 1;
    int m = lane & 15, q = lane >> 4;
    int sr = tid >> 2, sc = (tid & 3)*16;
    int jtb = (j0 >> 4) + wn*2;                     // wave's B j-tile base
    f32x4 acc[2][2];
    #pragma unroll
    for (int mt = 0; mt < 2; ++mt)
        #pragma unroll
        for (int nt = 0; nt < 2; ++nt) acc[mt][nt] = (f32x4){0.f,0.f,0.f,0.f};

    *(short8*)&Als[0][sr*72 + sc]     = *(const short8*)(Ab + (size_t)(i0+sr)*Nn + sc);
    *(short8*)&Als[0][sr*72 + sc + 8] = *(const short8*)(Ab + (size_t)(i0+sr)*Nn + sc + 8);
    short8 pa0 = *(const short8*)(Ab + (size_t)(i0+sr)*Nn + 64 + sc);
    short8 pa1 = *(const short8*)(Ab + (size_t)(i0+sr)*Nn + 64 + sc + 8);
    short8 bfr[2][2][2];                            // [slot][ks][nt], slot toggles with kt parity
    #pragma unroll
    for (int p = 0; p < 2; ++p)
        #pragma unroll
        for (int ks = 0; ks < 2; ++ks)
            #pragma unroll
            for (int nt = 0; nt < 2; ++nt)
                bfr[p][ks][nt] = *(const short8*)(pkB + (size_t)((p*2+ks)*32 + jtb + nt)*512);

    #pragma unroll
    for (int kt = 0; kt < 8; ++kt) {
        __syncthreads();                            // Als[kt&1] ready; prev readers of [kt^1] done
        if (kt < 7) {
            *(short8*)&Als[(kt+1)&1][sr*72 + sc]     = pa0;
            *(short8*)&Als[(kt+1)&1][sr*72 + sc + 8] = pa1;
        }
        if (kt < 6) {
            pa0 = *(const short8*)(Ab + (size_t)(i0+sr)*Nn + (kt+2)*64 + sc);
            pa1 = *(const short8*)(Ab + (size_t)(i0+sr)*Nn + (kt+2)*64 + sc + 8);
        }
        short8 cur[2][2];
        #pragma unroll
        for (int ks = 0; ks < 2; ++ks)
            #pragma unroll
            for (int nt = 0; nt < 2; ++nt) cur[ks][nt] = bfr[kt&1][ks][nt];
        if (kt < 6) {
            #pragma unroll
            for (int ks = 0; ks < 2; ++ks)
                #pragma unroll
                for (int nt = 0; nt < 2; ++nt)
                    bfr[kt&1][ks][nt] = *(const short8*)(pkB + (size_t)(((kt+2)*2+ks)*32 + jtb + nt)*512);
        }
        #pragma unroll
        for (int ks = 0; ks < 2; ++ks) {
            short8 af[2];
            #pragma unroll
            for (int mt = 0; mt < 2; ++mt)
                af[mt] = *(const short8*)&Als[kt&1][(wm*32+mt*16+m)*72 + ks*32 + q*8];
            #pragma unroll
            for (int mt = 0; mt < 2; ++mt)
                #pragma unroll
                for (int nt = 0; nt < 2; ++nt)
                    acc[mt][nt] = __builtin_amdgcn_mfma_f32_16x16x32_bf16(af[mt], cur[ks][nt], acc[mt][nt], 0, 0, 0);
        }
    }
    int col = lane & 15, rq = lane >> 4;
    #pragma unroll
    for (int mt = 0; mt < 2; ++mt)
        #pragma unroll
        for (int nt = 0; nt < 2; ++nt)
            #pragma unroll
            for (int reg = 0; reg < 4; ++reg) {
                int i = i0 + wm*32 + mt*16 + rq*4 + reg;
                int j = j0 + wn*32 + nt*16 + col;
                a2b[base + (size_t)i*Nn + j] = f2bf(acc[mt][nt][reg]);
            }
}

// ============ K4: out = (adj + 0.5*a2 + 0.25*(a2@adj)) / (max+1e-8), spin-fused norm ============
// Per-batch spin replaces the k_norm launch: 256 blocks = 1/CU (co-resident); each block
// atomicMax's its tile max, release-increments done[b], tid0 acquire-spins for done[b]==64,
// then the block writes e (still in registers) already normalized. Same inv and same f32 e
// values as the old k_norm path -> bit-identical output. (Numerics proven in R1's phase 3/4.)
__global__ __launch_bounds__(256) void k_mm2(
    const unsigned short* __restrict__ adj_b, const unsigned short* __restrict__ adj_pk,
    const unsigned short* __restrict__ a2b,
    float* __restrict__ out, unsigned int* __restrict__ maxslot, unsigned int* __restrict__ done)
{
    __shared__ unsigned short Als[2][64*72];
    __shared__ float red[4];
    __shared__ float invs;
    int tid = threadIdx.x;
    int wv = __builtin_amdgcn_readfirstlane(tid >> 6);
    int lane = tid & 63;
    int b = blockIdx.z, i0 = blockIdx.y*64, j0 = blockIdx.x*64;
    size_t base = (size_t)b << 18;
    const unsigned short* Ab = a2b + base;          // A = a2
    const unsigned short* pkB = adj_pk + base + (size_t)lane*8;
    int wm = wv >> 1, wn = wv & 1;
    int m = lane & 15, q = lane >> 4;
    int sr = tid >> 2, sc = (tid & 3)*16;
    int jtb = (j0 >> 4) + wn*2;
    f32x4 acc[2][2];
    #pragma unroll
    for (int mt = 0; mt < 2; ++mt)
        #pragma unroll
        for (int nt = 0; nt < 2; ++nt) acc[mt][nt] = (f32x4){0.f,0.f,0.f,0.f};

    *(short8*)&Als[0][sr*72 + sc]     = *(const short8*)(Ab + (size_t)(i0+sr)*Nn + sc);
    *(short8*)&Als[0][sr*72 + sc + 8] = *(const short8*)(Ab + (size_t)(i0+sr)*Nn + sc + 8);
    short8 pa0 = *(const short8*)(Ab + (size_t)(i0+sr)*Nn + 64 + sc);
    short8 pa1 = *(const short8*)(Ab + (size_t)(i0+sr)*Nn + 64 + sc + 8);
    short8 bfr[2][2][2];
    #pragma unroll
    for (int p = 0; p < 2; ++p)
        #pragma unroll
        for (int ks = 0; ks < 2; ++ks)
            #pragma unroll
            for (int nt = 0; nt < 2; ++nt)
                bfr[p][ks][nt] = *(const short8*)(pkB + (size_t)((p*2+ks)*32 + jtb + nt)*512);

    #pragma unroll
    for (int kt = 0; kt < 8; ++kt) {
        __syncthreads();
        if (kt < 7) {
            *(short8*)&Als[(kt+1)&1][sr*72 + sc]     = pa0;
            *(short8*)&Als[(kt+1)&1][sr*72 + sc + 8] = pa1;
        }
        if (kt < 6) {
            pa0 = *(const short8*)(Ab + (size_t)(i0+sr)*Nn + (kt+2)*64 + sc);
            pa1 = *(const short8*)(Ab + (size_t)(i0+sr)*Nn + (kt+2)*64 + sc + 8);
        }
        short8 cur[2][2];
        #pragma unroll
        for (int ks = 0; ks < 2; ++ks)
            #pragma unroll
            for (int nt = 0; nt < 2; ++nt) cur[ks][nt] = bfr[kt&1][ks][nt];
        if (kt < 6) {
            #pragma unroll
            for (int ks = 0; ks < 2; ++ks)
                #pragma unroll
                for (int nt = 0; nt < 2; ++nt)
                    bfr[kt&1][ks][nt] = *(const short8*)(pkB + (size_t)(((kt+2)*2+ks)*32 + jtb + nt)*512);
        }
        #pragma unroll
        for (int ks = 0; ks < 2; ++ks) {
            short8 af[2];
            #pragma unroll
            for (int mt = 0; mt < 2; ++mt)
                af[mt] = *(const short8*)&Als[kt&1][(wm*32+mt*16+m)*72 + ks*32 + q*8];
            #pragma unroll
            for (int mt = 0; mt < 2; ++mt)
                #pragma unroll
                for (int nt = 0; nt < 2; ++nt)
                    acc[mt][nt] = __builtin_amdgcn_mfma_f32_16x16x32_bf16(af[mt], cur[ks][nt], acc[mt][nt], 0, 0, 0);
        }
    }
    int col = lane & 15, rq = lane >> 4;
    float lmax = 0.f;
    const unsigned short* adjp = adj_b + base;
    #pragma unroll
    for (int mt = 0; mt < 2; ++mt)
        #pragma unroll
        for (int nt = 0; nt < 2; ++nt)
            #pragma unroll
            for (int reg = 0; reg < 4; ++reg) {
                int i = i0 + wm*32 + mt*16 + rq*4 + reg;
                int j = j0 + wn*32 + nt*16 + col;
                size_t off = (size_t)i*Nn + j;
                float e = bf2f(adjp[off]) + 0.5f*bf2f(Ab[off]) + 0.25f*acc[mt][nt][reg];
                acc[mt][nt][reg] = e;               // keep e in registers
                lmax = fmaxf(lmax, e);
            }
    #pragma unroll
    for (int s = 1; s < 64; s <<= 1) lmax = fmaxf(lmax, __shfl_xor(lmax, s, 64));
    if (lane == 0) red[wv] = lmax;
    __syncthreads();
    if (tid == 0) {
        float mx = fmaxf(fmaxf(red[0], red[1]), fmaxf(red[2], red[3]));
        atomicMax(maxslot + b, __float_as_uint(mx));               // device-scope
        __hip_atomic_fetch_add(done + b, 1u, __ATOMIC_ACQ_REL, __HIP_MEMORY_SCOPE_AGENT);
        while (__hip_atomic_load(done + b, __ATOMIC_ACQUIRE, __HIP_MEMORY_SCOPE_AGENT) < 64u)
            __builtin_amdgcn_s_sleep(1);
        unsigned int mu = __hip_atomic_load(maxslot + b, __ATOMIC_ACQUIRE, __HIP_MEMORY_SCOPE_AGENT);
        invs = 1.f / (__uint_as_float(mu) + 1e-8f);
    }
    __syncthreads();
    float inv = invs;
    #pragma unroll
    for (int mt = 0; mt < 2; ++mt)
        #pragma unroll
        for (int nt = 0; nt < 2; ++nt)
            #pragma unroll
            for (int reg = 0; reg < 4; ++reg) {
                int i = i0 + wm*32 + mt*16 + rq*4 + reg;
                int j = j0 + wn*32 + nt*16 + col;
                out[base + (size_t)i*Nn + j] = acc[mt][nt][reg] * inv;
            }
}

extern "C" void kernel_launch(void* const* d_in, const int* in_sizes, int n_in,
                              void* d_out, int out_size, void* d_ws, size_t ws_size,
                              hipStream_t stream) {
    const float* x   = (const float*)d_in[0];
    const float* W1  = (const float*)d_in[1];
    const float* b1  = (const float*)d_in[2];
    const float* W2  = (const float*)d_in[3];
    const float* b2  = (const float*)d_in[4];
    const float* Ws1 = (const float*)d_in[5];
    const float* bs1 = (const float*)d_in[6];
    const float* Ws2 = (const float*)d_in[7];
    const float* bs2 = (const float*)d_in[8];
    float* out = (float*)d_out;

    unsigned char* wsb = (unsigned char*)d_ws;
    unsigned short* spb    = (unsigned short*)(wsb);                    // 512 KB (f16)
    unsigned short* tpb    = (unsigned short*)(wsb + (512u<<10));       // 512 KB (f16)
    unsigned short* adj_b  = (unsigned short*)(wsb + (1024u<<10));      // 2 MB
    unsigned short* adj_pk = (unsigned short*)(wsb + (3072u<<10));      // 2 MB (fragment-packed)
    unsigned short* a2b    = (unsigned short*)(wsb + (5120u<<10));      // 2 MB
    unsigned int*   slots  = (unsigned int*)(wsb + (7168u<<10));        // 32 B: maxslot[4] + done[4]
    unsigned short* w1p    = (unsigned short*)(wsb + (7172u<<10));      // 64 KB
    unsigned short* w2p    = (unsigned short*)(wsb + (7236u<<10));      // 64 KB
    unsigned short* wsp    = (unsigned short*)(wsb + (7300u<<10));      // 64 KB
    unsigned int*   maxslot = slots;
    unsigned int*   done    = slots + 4;

    k_prep <<<dim3(48),       256, 0, stream>>>(W1, W2, Ws1, w1p, w2p, wsp);
    k_enc  <<<dim3(128),      512, 0, stream>>>(x, b1, b2, bs1, w1p, w2p, wsp, spb, tpb, slots);
    k_score<<<dim3(8, 8, Bn), 512, 0, stream>>>(spb, tpb, Ws2, bs2, adj_b, adj_pk);
    k_mm1  <<<dim3(8, 8, Bn), 256, 0, stream>>>(adj_b, adj_pk, a2b);
    k_mm2  <<<dim3(8, 8, Bn), 256, 0, stream>>>(adj_b, adj_pk, a2b, out, maxslot, done);
}

// Round 13
// 111.544 us; speedup vs baseline: 1.0754x; 1.0754x over previous
//
#include <hip/hip_runtime.h>
#include <math.h>

#define Bn 4
#define Tn 12
#define Nn 512
#define Dn 128
#define Ln 4
#define Hn 64

typedef __attribute__((ext_vector_type(8))) short short8;
typedef __attribute__((ext_vector_type(4))) float f32x4;
typedef _Float16 h2 __attribute__((ext_vector_type(2)));

__device__ __forceinline__ unsigned short f2bf(float f) {
    unsigned int u = __float_as_uint(f);
    unsigned int r = (u + 0x7FFF + ((u >> 16) & 1)) >> 16;   // RNE
    return (unsigned short)r;
}
__device__ __forceinline__ float bf2f(unsigned short s) {
    return __uint_as_float(((unsigned int)s) << 16);
}
__device__ __forceinline__ float fdot2(h2 a, h2 b, float c) {
#if defined(__has_builtin)
#if __has_builtin(__builtin_amdgcn_fdot2)
    return __builtin_amdgcn_fdot2(a, b, c, false);
#else
    return c + (float)a.x*(float)b.x + (float)a.y*(float)b.y;
#endif
#else
    return c + (float)a.x*(float)b.x + (float)a.y*(float)b.y;
#endif
}

// ============ K0: weight pre-pack (once): W1/W2/Ws1 -> bf16, MFMA-B layout ============
__global__ __launch_bounds__(256) void k_prep(
    const float* __restrict__ W1, const float* __restrict__ W2, const float* __restrict__ Ws1,
    unsigned short* __restrict__ w1p, unsigned short* __restrict__ w2p,
    unsigned short* __restrict__ wsp)
{
    int g = blockIdx.x*256 + threadIdx.x;
    unsigned short tmp[8];
    if (g < 4096) {                       // w1p
        int lag = g >> 10, r = g & 1023;
        int n = r >> 4, k8 = r & 15;
        #pragma unroll
        for (int j = 0; j < 8; ++j) tmp[j] = f2bf(W1[(size_t)(lag*128 + k8*8 + j)*64 + n]);
        *(short8*)(w1p + (size_t)lag*8192 + n*128 + k8*8) = *(const short8*)tmp;
    } else if (g < 8192) {                // w2p
        int r = g - 4096;
        int n = r >> 5, k8 = r & 31;
        #pragma unroll
        for (int j = 0; j < 8; ++j) tmp[j] = f2bf(W2[(size_t)(k8*8 + j)*128 + n]);
        *(short8*)(w2p + (size_t)n*256 + k8*8) = *(const short8*)tmp;
    } else {                              // wsp
        int r = g - 8192;
        int tgt = r >> 11, r2 = r & 2047;
        int n = r2 >> 4, k8 = r2 & 15;
        #pragma unroll
        for (int j = 0; j < 8; ++j) tmp[j] = f2bf(Ws1[(size_t)(tgt*128 + k8*8 + j)*128 + n]);
        *(short8*)(wsp + (size_t)tgt*16384 + n*128 + k8*8) = *(const short8*)tmp;
    }
}

// ============ K1: fused lag-encoder, 512 threads (R5, proven) ============
__global__ __launch_bounds__(512) void k_enc(
    const float* __restrict__ x,  const float* __restrict__ b1,
    const float* __restrict__ b2, const float* __restrict__ bs1,
    const unsigned short* __restrict__ w1p, const unsigned short* __restrict__ w2p,
    const unsigned short* __restrict__ wsp,
    unsigned short* __restrict__ spb, unsigned short* __restrict__ tpb,
    unsigned int* __restrict__ maxslot)
{
    __shared__ __align__(16) unsigned short xAll[4][16*136];
    __shared__ __align__(16) unsigned short hA[16*264];
    __shared__ __align__(16) unsigned short aggA[16*136];
    int tid  = threadIdx.x;
    int bid  = blockIdx.x;
    int wv   = __builtin_amdgcn_readfirstlane(tid >> 6);
    int lane = tid & 63;
    if (bid == 0 && tid < Bn) maxslot[tid] = 0u;

    int r0 = bid * 16;                      // never straddles a batch
    int bb = r0 >> 9, n0 = r0 & 511;
    int m = lane & 15, q = lane >> 4;
    int colL = lane & 15, rq = lane >> 4;

    // --- stage all 4 lag x-tiles ---
    for (int v = tid; v < 2048; v += 512) {
        int lag = v >> 9, r = v & 511;
        int row = r >> 5, c4 = r & 31;
        const float4* xs = (const float4*)(x + ((size_t)(bb*Tn + (Tn-1-lag))*Nn + n0)*Dn);
        float4 f = xs[row*32 + c4];
        ushort4 o = { f2bf(f.x), f2bf(f.y), f2bf(f.z), f2bf(f.w) };
        *(ushort4*)&xAll[lag][row*136 + c4*4] = o;
    }
    __syncthreads();

    // --- 1a: hA = relu(x_lag @ W1[lag] + b1[lag]); wave = (lag, 32-col half) ---
    {
        int lag = wv >> 1, hf = wv & 1;
        f32x4 acc[2] = {{0.f,0.f,0.f,0.f},{0.f,0.f,0.f,0.f}};
        #pragma unroll
        for (int ks = 0; ks < 4; ++ks) {
            short8 af = *(const short8*)&xAll[lag][m*136 + ks*32 + q*8];
            #pragma unroll
            for (int nt = 0; nt < 2; ++nt) {
                short8 bg = *(const short8*)(w1p + (size_t)lag*8192 + (hf*32 + nt*16 + m)*128 + ks*32 + q*8);
                acc[nt] = __builtin_amdgcn_mfma_f32_16x16x32_bf16(af, bg, acc[nt], 0, 0, 0);
            }
        }
        #pragma unroll
        for (int nt = 0; nt < 2; ++nt) {
            int ncol = hf*32 + nt*16 + colL;
            float bv = b1[lag*Hn + ncol];
            #pragma unroll
            for (int reg = 0; reg < 4; ++reg)
                hA[(rq*4+reg)*264 + lag*64 + ncol] = f2bf(fmaxf(acc[nt][reg] + bv, 0.f));
        }
    }
    __syncthreads();

    // --- 1b: aggA = 0.25*(hA @ W2stacked + sum_l b2[l]) ---
    {
        f32x4 acc = {0.f,0.f,0.f,0.f};
        #pragma unroll
        for (int ks = 0; ks < 8; ++ks) {
            short8 af = *(const short8*)&hA[m*264 + ks*32 + q*8];
            short8 bg = *(const short8*)(w2p + (size_t)(wv*16 + m)*256 + ks*32 + q*8);
            acc = __builtin_amdgcn_mfma_f32_16x16x32_bf16(af, bg, acc, 0, 0, 0);
        }
        int col = wv*16 + colL;
        float b2s = b2[col] + b2[Dn+col] + b2[2*Dn+col] + b2[3*Dn+col];
        #pragma unroll
        for (int reg = 0; reg < 4; ++reg)
            aggA[(rq*4+reg)*136 + col] = f2bf(0.25f*(acc[reg] + b2s));
    }
    __syncthreads();

    // --- 1c: sp/tp = aggA@Ws1; wave = (tgt, 32-col range) ---
    {
        int tgt = wv >> 2, wv4 = wv & 3;
        f32x4 acc[2] = {{0.f,0.f,0.f,0.f},{0.f,0.f,0.f,0.f}};
        #pragma unroll
        for (int ks = 0; ks < 4; ++ks) {
            short8 af = *(const short8*)&aggA[m*136 + ks*32 + q*8];
            #pragma unroll
            for (int nt = 0; nt < 2; ++nt) {
                short8 bg = *(const short8*)(wsp + (size_t)tgt*16384 + (wv4*32 + nt*16 + m)*128 + ks*32 + q*8);
                acc[nt] = __builtin_amdgcn_mfma_f32_16x16x32_bf16(af, bg, acc[nt], 0, 0, 0);
            }
        }
        unsigned short* dst = tgt ? tpb : spb;
        #pragma unroll
        for (int nt = 0; nt < 2; ++nt) {
            int n = wv4*32 + nt*16 + colL;
            float bv = tgt ? 0.f : bs1[n];
            #pragma unroll
            for (int reg = 0; reg < 4; ++reg) {
                _Float16 hv = (_Float16)(acc[nt][reg] + bv);
                dst[(size_t)(r0 + rq*4 + reg)*Dn + n] = __builtin_bit_cast(unsigned short, hv);
            }
        }
    }
}

// ============ K2: pairwise scorer, 512 threads (R11, proven) -> adj_b + adj_pk ============
__global__ __launch_bounds__(512) void k_score(
    const unsigned short* __restrict__ spb, const unsigned short* __restrict__ tpb,
    const float* __restrict__ Ws2, const float* __restrict__ bs2,
    unsigned short* __restrict__ adj_b, unsigned short* __restrict__ adj_pk)
{
    __shared__ unsigned int spl[64*65];     // f16 pairs, stride 65 uints (bank-safe)
    __shared__ unsigned int tpl[64*65];
    __shared__ unsigned int wl[64];
    int tid = threadIdx.x;
    int wv = __builtin_amdgcn_readfirstlane(tid >> 6);   // 0..7
    int lane = tid & 63;
    int bz = blockIdx.z;
    int i0b = blockIdx.y * 64, j0b = blockIdx.x * 64;
    const unsigned short* spr = spb + (size_t)bz*Nn*Dn;
    const unsigned short* tpr = tpb + (size_t)bz*Nn*Dn;

    for (int v = tid; v < 1024; v += 512) {           // both tiles, row-major f16 pairs
        int row = v >> 4, c = v & 15;
        uint4 gs = *(const uint4*)(spr + (size_t)(i0b+row)*Dn + c*8);
        uint4 gt = *(const uint4*)(tpr + (size_t)(j0b+row)*Dn + c*8);
        spl[row*65 + c*4 + 0] = gs.x; spl[row*65 + c*4 + 1] = gs.y;
        spl[row*65 + c*4 + 2] = gs.z; spl[row*65 + c*4 + 3] = gs.w;
        tpl[row*65 + c*4 + 0] = gt.x; tpl[row*65 + c*4 + 1] = gt.y;
        tpl[row*65 + c*4 + 2] = gt.z; tpl[row*65 + c*4 + 3] = gt.w;
    }
    if (tid < 64) {
        h2 hw = { (_Float16)Ws2[tid*2], (_Float16)Ws2[tid*2+1] };
        wl[tid] = __builtin_bit_cast(unsigned int, hw);
    }
    __syncthreads();

    int iq = lane >> 4, jq = lane & 15;
    int iw = wv*8 + iq*2;                             // 8 waves x 4 iq x 2 rows = 64 rows
    float acc[2][4] = {};
    #pragma unroll 4
    for (int c = 0; c < 64; ++c) {                    // one f16 d-pair per iter
        h2 wp = __builtin_bit_cast(h2, wl[c]);
        h2 sh[2], th[4];
        #pragma unroll
        for (int ii = 0; ii < 2; ++ii) sh[ii] = __builtin_bit_cast(h2, spl[(iw+ii)*65 + c]);
        #pragma unroll
        for (int jj = 0; jj < 4; ++jj) th[jj] = __builtin_bit_cast(h2, tpl[(jq*4+jj)*65 + c]);
        #pragma unroll
        for (int ii = 0; ii < 2; ++ii)
            #pragma unroll
            for (int jj = 0; jj < 4; ++jj) {
                h2 r = __builtin_elementwise_max(sh[ii] + th[jj], (h2){(_Float16)0.f,(_Float16)0.f});
                acc[ii][jj] = fdot2(r, wp, acc[ii][jj]);
            }
    }
    float bsv = bs2[0];
    int i0 = i0b + iw;
    int j0 = j0b + jq*4;
    float vals[2][4];
    #pragma unroll
    for (int ii = 0; ii < 2; ++ii) {
        int i = i0 + ii;
        #pragma unroll
        for (int jj = 0; jj < 4; ++jj) {
            float z = acc[ii][jj] + bsv;
            float sc = 1.f/(1.f + __expf(-z));
            int j = j0 + jj;
            vals[ii][jj] = (sc > 0.1f && i != j) ? sc : 0.f;
        }
    }
    size_t base = (size_t)bz << 18;
    #pragma unroll
    for (int ii = 0; ii < 2; ++ii) {
        ushort4 rv = make_ushort4(f2bf(vals[ii][0]), f2bf(vals[ii][1]),
                                  f2bf(vals[ii][2]), f2bf(vals[ii][3]));
        *(ushort4*)(adj_b + base + (size_t)(i0+ii)*Nn + j0) = rv;
    }
    // fragment-packed writes: per jj, the 2 ii values are t0..t0+1 of one octet (4B store)
    int kblk = i0 >> 5, qq = (i0 >> 3) & 3, t0 = i0 & 7;
    #pragma unroll
    for (int jj = 0; jj < 4; ++jj) {
        int j = j0 + jj;
        int jt = j >> 4, mm = j & 15;
        ushort2 cv = make_ushort2(f2bf(vals[0][jj]), f2bf(vals[1][jj]));
        *(ushort2*)(adj_pk + base + (size_t)(kblk*32 + jt)*512 + (qq*16 + mm)*8 + t0) = cv;
    }
}

// ============ K3: a2 = adj @ adj; A via LDS dbuf (1 barrier/kt), B direct from adj_pk ============
// kt loop fully unrolled: all bfr[] indices compile-time (rule #20 — no scratch). R10-proven.
__global__ __launch_bounds__(256) void k_mm1(
    const unsigned short* __restrict__ adj_b, const unsigned short* __restrict__ adj_pk,
    unsigned short* __restrict__ a2b)
{
    __shared__ unsigned short Als[2][64*72];
    int tid = threadIdx.x;
    int wv = __builtin_amdgcn_readfirstlane(tid >> 6);
    int lane = tid & 63;
    int b = blockIdx.z, i0 = blockIdx.y*64, j0 = blockIdx.x*64;
    size_t base = (size_t)b << 18;
    const unsigned short* Ab = adj_b + base;
    const unsigned short* pkB = adj_pk + base + (size_t)lane*8;
    int wm = wv >> 1, wn = wv & 1;
    int m = lane & 15, q = lane >> 4;
    int sr = tid >> 2, sc = (tid & 3)*16;
    int jtb = (j0 >> 4) + wn*2;                     // wave's B j-tile base
    f32x4 acc[2][2];
    #pragma unroll
    for (int mt = 0; mt < 2; ++mt)
        #pragma unroll
        for (int nt = 0; nt < 2; ++nt) acc[mt][nt] = (f32x4){0.f,0.f,0.f,0.f};

    *(short8*)&Als[0][sr*72 + sc]     = *(const short8*)(Ab + (size_t)(i0+sr)*Nn + sc);
    *(short8*)&Als[0][sr*72 + sc + 8] = *(const short8*)(Ab + (size_t)(i0+sr)*Nn + sc + 8);
    short8 pa0 = *(const short8*)(Ab + (size_t)(i0+sr)*Nn + 64 + sc);
    short8 pa1 = *(const short8*)(Ab + (size_t)(i0+sr)*Nn + 64 + sc + 8);
    short8 bfr[2][2][2];                            // [slot][ks][nt], slot toggles with kt parity
    #pragma unroll
    for (int p = 0; p < 2; ++p)
        #pragma unroll
        for (int ks = 0; ks < 2; ++ks)
            #pragma unroll
            for (int nt = 0; nt < 2; ++nt)
                bfr[p][ks][nt] = *(const short8*)(pkB + (size_t)((p*2+ks)*32 + jtb + nt)*512);

    #pragma unroll
    for (int kt = 0; kt < 8; ++kt) {
        __syncthreads();                            // Als[kt&1] ready; prev readers of [kt^1] done
        if (kt < 7) {
            *(short8*)&Als[(kt+1)&1][sr*72 + sc]     = pa0;
            *(short8*)&Als[(kt+1)&1][sr*72 + sc + 8] = pa1;
        }
        if (kt < 6) {
            pa0 = *(const short8*)(Ab + (size_t)(i0+sr)*Nn + (kt+2)*64 + sc);
            pa1 = *(const short8*)(Ab + (size_t)(i0+sr)*Nn + (kt+2)*64 + sc + 8);
        }
        short8 cur[2][2];
        #pragma unroll
        for (int ks = 0; ks < 2; ++ks)
            #pragma unroll
            for (int nt = 0; nt < 2; ++nt) cur[ks][nt] = bfr[kt&1][ks][nt];
        if (kt < 6) {
            #pragma unroll
            for (int ks = 0; ks < 2; ++ks)
                #pragma unroll
                for (int nt = 0; nt < 2; ++nt)
                    bfr[kt&1][ks][nt] = *(const short8*)(pkB + (size_t)(((kt+2)*2+ks)*32 + jtb + nt)*512);
        }
        #pragma unroll
        for (int ks = 0; ks < 2; ++ks) {
            short8 af[2];
            #pragma unroll
            for (int mt = 0; mt < 2; ++mt)
                af[mt] = *(const short8*)&Als[kt&1][(wm*32+mt*16+m)*72 + ks*32 + q*8];
            #pragma unroll
            for (int mt = 0; mt < 2; ++mt)
                #pragma unroll
                for (int nt = 0; nt < 2; ++nt)
                    acc[mt][nt] = __builtin_amdgcn_mfma_f32_16x16x32_bf16(af[mt], cur[ks][nt], acc[mt][nt], 0, 0, 0);
        }
    }
    int col = lane & 15, rq = lane >> 4;
    #pragma unroll
    for (int mt = 0; mt < 2; ++mt)
        #pragma unroll
        for (int nt = 0; nt < 2; ++nt)
            #pragma unroll
            for (int reg = 0; reg < 4; ++reg) {
                int i = i0 + wm*32 + mt*16 + rq*4 + reg;
                int j = j0 + wn*32 + nt*16 + col;
                a2b[base + (size_t)i*Nn + j] = f2bf(acc[mt][nt][reg]);
            }
}

// ============ K4: out = adj + 0.5*a2 + 0.25*(a2@adj); A=a2 LDS dbuf, B=adj_pk direct ============
__global__ __launch_bounds__(256) void k_mm2(
    const unsigned short* __restrict__ adj_b, const unsigned short* __restrict__ adj_pk,
    const unsigned short* __restrict__ a2b,
    float* __restrict__ out, unsigned int* __restrict__ maxslot)
{
    __shared__ unsigned short Als[2][64*72];
    __shared__ float red[4];
    int tid = threadIdx.x;
    int wv = __builtin_amdgcn_readfirstlane(tid >> 6);
    int lane = tid & 63;
    int b = blockIdx.z, i0 = blockIdx.y*64, j0 = blockIdx.x*64;
    size_t base = (size_t)b << 18;
    const unsigned short* Ab = a2b + base;          // A = a2
    const unsigned short* pkB = adj_pk + base + (size_t)lane*8;
    int wm = wv >> 1, wn = wv & 1;
    int m = lane & 15, q = lane >> 4;
    int sr = tid >> 2, sc = (tid & 3)*16;
    int jtb = (j0 >> 4) + wn*2;
    f32x4 acc[2][2];
    #pragma unroll
    for (int mt = 0; mt < 2; ++mt)
        #pragma unroll
        for (int nt = 0; nt < 2; ++nt) acc[mt][nt] = (f32x4){0.f,0.f,0.f,0.f};

    *(short8*)&Als[0][sr*72 + sc]     = *(const short8*)(Ab + (size_t)(i0+sr)*Nn + sc);
    *(short8*)&Als[0][sr*72 + sc + 8] = *(const short8*)(Ab + (size_t)(i0+sr)*Nn + sc + 8);
    short8 pa0 = *(const short8*)(Ab + (size_t)(i0+sr)*Nn + 64 + sc);
    short8 pa1 = *(const short8*)(Ab + (size_t)(i0+sr)*Nn + 64 + sc + 8);
    short8 bfr[2][2][2];
    #pragma unroll
    for (int p = 0; p < 2; ++p)
        #pragma unroll
        for (int ks = 0; ks < 2; ++ks)
            #pragma unroll
            for (int nt = 0; nt < 2; ++nt)
                bfr[p][ks][nt] = *(const short8*)(pkB + (size_t)((p*2+ks)*32 + jtb + nt)*512);

    #pragma unroll
    for (int kt = 0; kt < 8; ++kt) {
        __syncthreads();
        if (kt < 7) {
            *(short8*)&Als[(kt+1)&1][sr*72 + sc]     = pa0;
            *(short8*)&Als[(kt+1)&1][sr*72 + sc + 8] = pa1;
        }
        if (kt < 6) {
            pa0 = *(const short8*)(Ab + (size_t)(i0+sr)*Nn + (kt+2)*64 + sc);
            pa1 = *(const short8*)(Ab + (size_t)(i0+sr)*Nn + (kt+2)*64 + sc + 8);
        }
        short8 cur[2][2];
        #pragma unroll
        for (int ks = 0; ks < 2; ++ks)
            #pragma unroll
            for (int nt = 0; nt < 2; ++nt) cur[ks][nt] = bfr[kt&1][ks][nt];
        if (kt < 6) {
            #pragma unroll
            for (int ks = 0; ks < 2; ++ks)
                #pragma unroll
                for (int nt = 0; nt < 2; ++nt)
                    bfr[kt&1][ks][nt] = *(const short8*)(pkB + (size_t)(((kt+2)*2+ks)*32 + jtb + nt)*512);
        }
        #pragma unroll
        for (int ks = 0; ks < 2; ++ks) {
            short8 af[2];
            #pragma unroll
            for (int mt = 0; mt < 2; ++mt)
                af[mt] = *(const short8*)&Als[kt&1][(wm*32+mt*16+m)*72 + ks*32 + q*8];
            #pragma unroll
            for (int mt = 0; mt < 2; ++mt)
                #pragma unroll
                for (int nt = 0; nt < 2; ++nt)
                    acc[mt][nt] = __builtin_amdgcn_mfma_f32_16x16x32_bf16(af[mt], cur[ks][nt], acc[mt][nt], 0, 0, 0);
        }
    }
    int col = lane & 15, rq = lane >> 4;
    float lmax = 0.f;
    const unsigned short* adjp = adj_b + base;
    #pragma unroll
    for (int mt = 0; mt < 2; ++mt)
        #pragma unroll
        for (int nt = 0; nt < 2; ++nt)
            #pragma unroll
            for (int reg = 0; reg < 4; ++reg) {
                int i = i0 + wm*32 + mt*16 + rq*4 + reg;
                int j = j0 + wn*32 + nt*16 + col;
                size_t off = (size_t)i*Nn + j;
                float e = bf2f(adjp[off]) + 0.5f*bf2f(Ab[off]) + 0.25f*acc[mt][nt][reg];
                out[base + off] = e;
                lmax = fmaxf(lmax, e);
            }
    #pragma unroll
    for (int s = 1; s < 64; s <<= 1) lmax = fmaxf(lmax, __shfl_xor(lmax, s, 64));
    if (lane == 0) red[wv] = lmax;
    __syncthreads();
    if (tid == 0) {
        float mx = fmaxf(fmaxf(red[0], red[1]), fmaxf(red[2], red[3]));
        atomicMax(maxslot + b, __float_as_uint(mx));
    }
}

// ============ K5: out /= (max + 1e-8) ============
__global__ __launch_bounds__(256) void k_norm(float* __restrict__ out,
                                              const unsigned int* __restrict__ maxslot)
{
    int idx = blockIdx.x*256 + threadIdx.x;   // float4 index; 65536 per batch
    int b = idx >> 16;
    float m = __uint_as_float(maxslot[b]);
    float inv = 1.f/(m + 1e-8f);
    float4* p = (float4*)out + idx;
    float4 v = *p;
    v.x *= inv; v.y *= inv; v.z *= inv; v.w *= inv;
    *p = v;
}

extern "C" void kernel_launch(void* const* d_in, const int* in_sizes, int n_in,
                              void* d_out, int out_size, void* d_ws, size_t ws_size,
                              hipStream_t stream) {
    const float* x   = (const float*)d_in[0];
    const float* W1  = (const float*)d_in[1];
    const float* b1  = (const float*)d_in[2];
    const float* W2  = (const float*)d_in[3];
    const float* b2  = (const float*)d_in[4];
    const float* Ws1 = (const float*)d_in[5];
    const float* bs1 = (const float*)d_in[6];
    const float* Ws2 = (const float*)d_in[7];
    const float* bs2 = (const float*)d_in[8];
    float* out = (float*)d_out;

    unsigned char* wsb = (unsigned char*)d_ws;
    unsigned short* spb    = (unsigned short*)(wsb);                    // 512 KB (f16)
    unsigned short* tpb    = (unsigned short*)(wsb + (512u<<10));       // 512 KB (f16)
    unsigned short* adj_b  = (unsigned short*)(wsb + (1024u<<10));      // 2 MB
    unsigned short* adj_pk = (unsigned short*)(wsb + (3072u<<10));      // 2 MB (fragment-packed)
    unsigned short* a2b    = (unsigned short*)(wsb + (5120u<<10));      // 2 MB
    unsigned int*   maxslot= (unsigned int*)(wsb + (7168u<<10));        // 16 B
    unsigned short* w1p    = (unsigned short*)(wsb + (7172u<<10));      // 64 KB
    unsigned short* w2p    = (unsigned short*)(wsb + (7236u<<10));      // 64 KB
    unsigned short* wsp    = (unsigned short*)(wsb + (7300u<<10));      // 64 KB

    k_prep <<<dim3(48),       256, 0, stream>>>(W1, W2, Ws1, w1p, w2p, wsp);
    k_enc  <<<dim3(128),      512, 0, stream>>>(x, b1, b2, bs1, w1p, w2p, wsp, spb, tpb, maxslot);
    k_score<<<dim3(8, 8, Bn), 512, 0, stream>>>(spb, tpb, Ws2, bs2, adj_b, adj_pk);
    k_mm1  <<<dim3(8, 8, Bn), 256, 0, stream>>>(adj_b, adj_pk, a2b);
    k_mm2  <<<dim3(8, 8, Bn), 256, 0, stream>>>(adj_b, adj_pk, a2b, out, maxslot);
    k_norm <<<dim3(1024),     256, 0, stream>>>(out, maxslot);
}